// Round 11
// baseline (311.878 us; speedup 1.0000x reference)
//
#include <hip/hip_runtime.h>
#include <hip/hip_fp16.h>
#include <cstdint>

#define N_NODES 100000
#define N_EDGES 1600000
#define F_IN 128
#define HID 128
#define N_CLS 40
#define BSHIFT 7
#define NBUCK ((N_NODES + 127) >> 7)   // 782 buckets of 128 dst nodes
#define CCHUNK 4096                     // edges per scatter block
#define FUSED_LDS 52224                 // max(scatter 45280, gemm-NT8 52224)

typedef _Float16 f16x8 __attribute__((ext_vector_type(8)));
typedef __attribute__((ext_vector_type(4))) float f32x4;
typedef __attribute__((ext_vector_type(2))) float f32x2;

__device__ __forceinline__ unsigned short f2h(float f) {
    return __builtin_bit_cast(unsigned short, (_Float16)f);
}
__device__ __forceinline__ __half2 u2h(unsigned u) { return __builtin_bit_cast(__half2, u); }

// fp8 (OCP e4m3 on gfx950) pack/unpack via HW converts
__device__ __forceinline__ f32x2 fp8_lo(unsigned u) { return __builtin_amdgcn_cvt_pk_f32_fp8((int)u, false); }
__device__ __forceinline__ f32x2 fp8_hi(unsigned u) { return __builtin_amdgcn_cvt_pk_f32_fp8((int)u, true); }
__device__ __forceinline__ unsigned char f2e(float v) {
    return (unsigned char)(__builtin_amdgcn_cvt_pk_fp8_f32(v, v, 0, false) & 0xff);
}

// ---------------------------------------------------------------------------
// Edge dtype detection (int64 vs int32 edge_index). Deterministic.
// ---------------------------------------------------------------------------
__global__ __launch_bounds__(256) void k_detect(const int* __restrict__ e, int* __restrict__ flag) {
    __shared__ int sor;
    if (threadIdx.x == 0) sor = 0;
    __syncthreads();
    atomicOr(&sor, e[threadIdx.x * 2 + 1]);
    __syncthreads();
    if (threadIdx.x == 0) flag[0] = (sor == 0) ? 1 : 0;  // 1 = int64 layout
}

__device__ __forceinline__ int edge_at(const int* e, const int* flag, int which, int i) {
    return flag[0] ? e[2 * ((size_t)which * N_EDGES + i)] : e[(size_t)which * N_EDGES + i];
}

// ---------------------------------------------------------------------------
// Bucketed CSR build. Phase A: per-bucket histogram.
// ---------------------------------------------------------------------------
__global__ __launch_bounds__(256) void k_hist(const int* __restrict__ e, const int* __restrict__ flag,
                                              int* __restrict__ bcnt, int E) {
    __shared__ int h[NBUCK];
    for (int i = threadIdx.x; i < NBUCK; i += 256) h[i] = 0;
    __syncthreads();
    for (int i = blockIdx.x * 256 + threadIdx.x; i < E; i += gridDim.x * 256) {
        int d = edge_at(e, flag, 1, i);
        atomicAdd(&h[d >> BSHIFT], 1);
    }
    __syncthreads();
    for (int i = threadIdx.x; i < NBUCK; i += 256)
        if (h[i]) atomicAdd(&bcnt[i], h[i]);
}

// Phase B: single-block scan of bucket counts -> bucket bases + cursors.
__global__ __launch_bounds__(1024) void k_bscan(const int* __restrict__ bcnt, int* __restrict__ bbase,
                                                int* __restrict__ bcur, int E) {
    __shared__ int s0[1024], s1[1024];
    int t = threadIdx.x;
    s0[t] = (t < NBUCK) ? bcnt[t] : 0;
    __syncthreads();
    int* src = s0;
    int* dst = s1;
    for (int off = 1; off < 1024; off <<= 1) {
        dst[t] = src[t] + ((t >= off) ? src[t - off] : 0);
        __syncthreads();
        int* tmp = src; src = dst; dst = tmp;
    }
    if (t < NBUCK) {
        int ex = t ? src[t - 1] : 0;
        bbase[t] = ex;
        bcur[t]  = ex;
    }
    if (t == 0) bbase[NBUCK] = E;
}

// Phase C body: LDS-binned scatter; global eb packed as (s<<7)|(d&127).
__device__ __forceinline__ void scatter_body(char* smem, const int* __restrict__ e,
                                             const int* __restrict__ flag, int* __restrict__ bcur,
                                             unsigned* __restrict__ eb, int E, int blk) {
    uint2* st  = (uint2*)smem;              // 32768 B
    int* hA    = (int*)(smem + 32768);      // NBUCK ints each
    int* hB    = hA + NBUCK;
    int* cur   = hB + NBUCK;
    int* runb  = cur + NBUCK;
    const int t    = threadIdx.x;
    const int base = blk * CCHUNK;
    const int len  = min(CCHUNK, E - base);

    for (int i = t; i < NBUCK; i += 256) hA[i] = 0;
    __syncthreads();
    for (int i = t; i < len; i += 256) {
        int d = edge_at(e, flag, 1, base + i);
        atomicAdd(&hA[d >> BSHIFT], 1);
    }
    __syncthreads();
    int* src = hA;
    int* dst = hB;
    for (int off = 1; off < NBUCK; off <<= 1) {
        for (int i = t; i < NBUCK; i += 256)
            dst[i] = src[i] + ((i >= off) ? src[i - off] : 0);
        __syncthreads();
        int* tmp = src; src = dst; dst = tmp;
    }
    for (int i = t; i < NBUCK; i += 256) {
        int inc = src[i];
        int ex  = i ? src[i - 1] : 0;
        dst[i] = ex;
        cur[i] = ex;
        int c = inc - ex;
        if (c) runb[i] = atomicAdd(&bcur[i], c);
    }
    __syncthreads();
    for (int i = t; i < len; i += 256) {
        int s = edge_at(e, flag, 0, base + i);
        int d = edge_at(e, flag, 1, base + i);
        int pos = atomicAdd(&cur[d >> BSHIFT], 1);
        st[pos] = make_uint2((unsigned)s, (unsigned)d);
    }
    __syncthreads();
    for (int i = t; i < len; i += 256) {
        uint2 v = st[i];
        int   b = (int)(v.y >> BSHIFT);
        int   gpos = runb[b] + (i - dst[b]);
        eb[gpos] = (v.x << 7) | (v.y & 127u);
    }
}

// Phase D: one block per bucket; exact per-dst CSR; fuses degree->dis/rowptr.
__global__ __launch_bounds__(256) void k_build(const int* __restrict__ bbase, const unsigned* __restrict__ eb,
                                               int* __restrict__ rowptr, int* __restrict__ es,
                                               float* __restrict__ dis, int N, int E) {
    __shared__ int c0[128], c1[128], cur[128];
    const int b  = blockIdx.x;
    const int t  = threadIdx.x;
    const int lo = bbase[b], hi = bbase[b + 1];

    if (t < 128) c0[t] = 0;
    __syncthreads();
    for (int i = lo + t; i < hi; i += 256) atomicAdd(&c0[eb[i] & 127u], 1);
    __syncthreads();
    int* src = c0;
    int* dst = c1;
    for (int off = 1; off < 128; off <<= 1) {
        if (t < 128) dst[t] = src[t] + ((t >= off) ? src[t - off] : 0);
        __syncthreads();
        int* tmp = src; src = dst; dst = tmp;
    }
    if (t < 128) {
        int inc = src[t], ex = t ? src[t - 1] : 0;
        int node = (b << BSHIFT) + t;
        if (node < N) {
            rowptr[node] = lo + ex;
            dis[node]    = rsqrtf((float)(inc - ex + 1));
        }
        cur[t] = ex;
    }
    if (b == 0 && t == 0) rowptr[N] = E;
    __syncthreads();
    for (int i = lo + t; i < hi; i += 256) {
        unsigned v = eb[i];
        int pos = atomicAdd(&cur[v & 127u], 1);
        es[lo + pos] = (int)(v >> 7);
    }
}

// Wt[col][k] = f16(W[k][col]), zero-padded to outp cols
__global__ __launch_bounds__(256) void k_wt(const float* __restrict__ W, unsigned short* __restrict__ Wt,
                                            int outc, int outp) {
    int idx = blockIdx.x * 256 + threadIdx.x;
    if (idx >= outp * 128) return;
    int col = idx >> 7, k = idx & 127;
    Wt[idx] = (col < outc) ? f2h(W[(size_t)k * outc + col]) : (unsigned short)0;
}

// ---------------------------------------------------------------------------
// MFMA f16 GEMM core. INMODE: 0 = fp32 in, 1 = f16 in. OUTMODE: 0 = f16 out
// [N,128] + fp8 copy (prescaled by dis[row] when dis8 != null); 2 = fused
// bias + log_softmax, fp32 out [N,outc]. Block = 64 rows, 4 waves x 16 rows.
// ---------------------------------------------------------------------------
template <int NT, int INMODE, int OUTMODE>
__device__ __forceinline__ void gemm_core(char* smemraw, const void* __restrict__ Xv,
                                          const unsigned short* __restrict__ Wt,
                                          void* __restrict__ HoutV, unsigned char* __restrict__ O8,
                                          const float* __restrict__ dis8,
                                          const float* __restrict__ bias, int N, int outc, int blk) {
    constexpr int OUTP = NT * 16;
    unsigned short* sX = (unsigned short*)smemraw;   // 64*136
    unsigned short* sW = sX + 64 * 136;              // OUTP*136
    const int tid  = threadIdx.x;
    const int row0 = blk * 64;

    if (INMODE == 0) {
        const float* X = (const float*)Xv;
        for (int c = tid; c < 64 * 16; c += 256) {
            int r = c >> 4, off = c & 15, row = row0 + r;
            unsigned short tmp[8];
            if (row < N) {
                const float* p = X + (size_t)row * 128 + off * 8;
                const float4 pa = *(const float4*)p;
                const float4 pb = *(const float4*)(p + 4);
                tmp[0] = f2h(pa.x); tmp[1] = f2h(pa.y); tmp[2] = f2h(pa.z); tmp[3] = f2h(pa.w);
                tmp[4] = f2h(pb.x); tmp[5] = f2h(pb.y); tmp[6] = f2h(pb.z); tmp[7] = f2h(pb.w);
            } else {
#pragma unroll
                for (int j = 0; j < 8; ++j) tmp[j] = 0;
            }
            *(uint4*)(&sX[r * 136 + off * 8]) = *(uint4*)tmp;
        }
    } else {
        const unsigned short* X = (const unsigned short*)Xv;
        for (int c = tid; c < 64 * 16; c += 256) {
            int r = c >> 4, off = c & 15, row = row0 + r;
            uint4 v = make_uint4(0, 0, 0, 0);
            if (row < N) v = *(const uint4*)(X + (size_t)row * 128 + off * 8);
            *(uint4*)(&sX[r * 136 + off * 8]) = v;
        }
    }
    for (int c = tid; c < OUTP * 16; c += 256) {
        int r = c >> 4, off = c & 15;
        *(uint4*)(&sW[r * 136 + off * 8]) = *(const uint4*)(Wt + (size_t)r * 128 + off * 8);
    }
    __syncthreads();

    const int wave = tid >> 6, lane = tid & 63;
    const int l15 = lane & 15, g = lane >> 4;
    const int arow = (wave << 4) + l15;

    f32x4 acc[NT];
#pragma unroll
    for (int n = 0; n < NT; ++n) acc[n] = (f32x4){0.f, 0.f, 0.f, 0.f};

#pragma unroll
    for (int kk = 0; kk < 4; ++kk) {
        f16x8 a = *(const f16x8*)(&sX[arow * 136 + kk * 32 + g * 8]);
#pragma unroll
        for (int n = 0; n < NT; ++n) {
            f16x8 b = *(const f16x8*)(&sW[(n * 16 + l15) * 136 + kk * 32 + g * 8]);
            acc[n] = __builtin_amdgcn_mfma_f32_16x16x32_f16(a, b, acc[n], 0, 0, 0);
        }
    }

    if (OUTMODE == 0) {
        unsigned short* O = (unsigned short*)HoutV;
        float sc4[4];
#pragma unroll
        for (int r = 0; r < 4; ++r) {
            int row = row0 + (wave << 4) + g * 4 + r;
            sc4[r] = (dis8 && row < N) ? dis8[row] : 1.0f;
        }
#pragma unroll
        for (int n = 0; n < NT; ++n) {
#pragma unroll
            for (int r = 0; r < 4; ++r) {
                int row = row0 + (wave << 4) + g * 4 + r;
                if (row < N) {
                    O[(size_t)row * 128 + n * 16 + l15]  = f2h(acc[n][r]);
                    O8[(size_t)row * 128 + n * 16 + l15] = f2e(acc[n][r] * sc4[r]);
                }
            }
        }
    } else {
        // fused bias + log_softmax epilogue
        float* O = (float*)HoutV;
#pragma unroll
        for (int r = 0; r < 4; ++r) {
            int row = row0 + (wave << 4) + g * 4 + r;
            float v[NT];
            float m = -3.0e38f;
#pragma unroll
            for (int n = 0; n < NT; ++n) {
                int col = n * 16 + l15;
                v[n] = (col < outc) ? acc[n][r] + bias[col] : -3.0e38f;
                m = fmaxf(m, v[n]);
            }
            for (int off = 8; off; off >>= 1) m = fmaxf(m, __shfl_xor(m, off));
            float ssum = 0.f;
#pragma unroll
            for (int n = 0; n < NT; ++n) {
                int col = n * 16 + l15;
                ssum += (col < outc) ? __expf(v[n] - m) : 0.f;
            }
            for (int off = 8; off; off >>= 1) ssum += __shfl_xor(ssum, off);
            float ls = __logf(ssum);
            if (row < N) {
#pragma unroll
                for (int n = 0; n < NT; ++n) {
                    int col = n * 16 + l15;
                    if (col < outc) O[(size_t)row * outc + col] = v[n] - m - ls;
                }
            }
        }
    }
}

template <int NT, int INMODE, int OUTMODE>
__global__ __launch_bounds__(256) void k_gemm_mfma(const void* __restrict__ Xv,
                                                   const unsigned short* __restrict__ Wt,
                                                   void* __restrict__ HoutV, unsigned char* __restrict__ O8,
                                                   const float* __restrict__ dis8,
                                                   const float* __restrict__ bias, int N, int outc) {
    constexpr int SZ = 64 * 136 * 2 + NT * 16 * 136 * 2;
    __shared__ __align__(16) char smem[SZ];
    gemm_core<NT, INMODE, OUTMODE>(smem, Xv, Wt, HoutV, O8, dis8, bias, N, outc, blockIdx.x);
}

// Fused: CSR scatter (blocks [0,nscat)) || layer-1 GEMM (blocks [nscat, ...)).
__global__ __launch_bounds__(256) void k_scat_gemm1(const int* __restrict__ e, const int* __restrict__ flag,
                                                    int* __restrict__ bcur, unsigned* __restrict__ eb, int E,
                                                    int nscat, const float* __restrict__ x,
                                                    const unsigned short* __restrict__ Wt1,
                                                    unsigned short* __restrict__ B1b,
                                                    unsigned char* __restrict__ B1e, int N) {
    extern __shared__ __align__(16) char smem[];
    if ((int)blockIdx.x < nscat)
        scatter_body(smem, e, flag, bcur, eb, E, blockIdx.x);
    else
        gemm_core<8, 0, 0>(smem, x, Wt1, B1b, B1e, nullptr, nullptr, N, 128, blockIdx.x - nscat);
}

// ---------------------------------------------------------------------------
// CSR pull, 8-slot uint4 gather: lane = (edge-slot q = lane>>3, feat-hexadec
// f = lane&7). One uint4 (16 fp8 feats) per lane -> a wave covers 8 edges per
// load instruction. PRE = rows pre-scaled by dis[src] (pure-add inner loop).
// Cross-slot reduce: shfl_xor 32/16/8; epilogue on 8 lanes x 16 feats.
// ---------------------------------------------------------------------------
#define PDEC(u)                                                              \
    a0 += fp8_lo(u.x); a1 += fp8_hi(u.x); a2 += fp8_lo(u.y); a3 += fp8_hi(u.y); \
    a4 += fp8_lo(u.z); a5 += fp8_hi(u.z); a6 += fp8_lo(u.w); a7 += fp8_hi(u.w);
#define PDECN(u, nn)                                                         \
    a0 += fp8_lo(u.x) * nn; a1 += fp8_hi(u.x) * nn;                          \
    a2 += fp8_lo(u.y) * nn; a3 += fp8_hi(u.y) * nn;                          \
    a4 += fp8_lo(u.z) * nn; a5 += fp8_hi(u.z) * nn;                          \
    a6 += fp8_lo(u.w) * nn; a7 += fp8_hi(u.w) * nn;

#define PSTEP(JJ)                                                            \
    {                                                                        \
        int s = __shfl(sv, (JJ) + q);                                        \
        const uint4 u = *(const uint4*)(H8 + (size_t)s * 128 + f * 16);      \
        if (PRE) { PDEC(u) }                                                 \
        else { float n = __shfl(nv, (JJ) + q); f32x2 nn = {n, n}; PDECN(u, nn) } \
    }

#define PSTEPC(JJ)                                                           \
    {                                                                        \
        int  idx = (JJ) + q;                                                 \
        bool ok  = idx < len;                                                \
        int  s   = __shfl(sv, ok ? idx : len - 1);                           \
        uint4 u  = *(const uint4*)(H8 + (size_t)s * 128 + f * 16);           \
        if (!ok) { u.x = 0u; u.y = 0u; u.z = 0u; u.w = 0u; }                 \
        if (PRE) { PDEC(u) }                                                 \
        else { float n = __shfl(nv, ok ? idx : len - 1); f32x2 nn = {n, n}; PDECN(u, nn) } \
    }

#define SLOT_REDUCE(A, M) { A.x += __shfl_xor(A.x, M); A.y += __shfl_xor(A.y, M); }

// Standalone pull. PRE = add path; RELU_BIAS for layers 1/2; W8 writes fp8
// copy pre-scaled by dis[node] for the next pull.
template <bool PRE, bool RELU_BIAS, bool W8>
__global__ __launch_bounds__(256) void k_pull128(const int* __restrict__ rowptr, const int* __restrict__ es,
                                                 const float* __restrict__ dis,
                                                 const unsigned char* __restrict__ H8,
                                                 const unsigned short* __restrict__ Hf,
                                                 const float* __restrict__ bias,
                                                 unsigned short* __restrict__ Outf,
                                                 unsigned char* __restrict__ Out8, int N) {
    int node = blockIdx.x * 4 + (threadIdx.x >> 6);
    if (node >= N) return;
    const int lane = threadIdx.x & 63;
    const int q = lane >> 3, f = lane & 7;
    const float dd = dis[node];

    f32x2 a0 = {0.f, 0.f}, a1 = a0, a2 = a0, a3 = a0, a4 = a0, a5 = a0, a6 = a0, a7 = a0;

    const int beg = rowptr[node], end = rowptr[node + 1];
    for (int c = beg; c < end; c += 64) {
        int len = end - c;
        if (len > 64) len = 64;
        int   sv = es[c + (lane < len ? lane : len - 1)];
        float nv = 0.f;
        if (!PRE) nv = dis[sv] * dd;
        int j = 0;
        for (; j + 16 <= len; j += 16) { PSTEP(j) PSTEP(j + 8) }
        for (; j < len; j += 8) PSTEPC(j)
    }

    SLOT_REDUCE(a0, 32) SLOT_REDUCE(a1, 32) SLOT_REDUCE(a2, 32) SLOT_REDUCE(a3, 32)
    SLOT_REDUCE(a4, 32) SLOT_REDUCE(a5, 32) SLOT_REDUCE(a6, 32) SLOT_REDUCE(a7, 32)
    SLOT_REDUCE(a0, 16) SLOT_REDUCE(a1, 16) SLOT_REDUCE(a2, 16) SLOT_REDUCE(a3, 16)
    SLOT_REDUCE(a4, 16) SLOT_REDUCE(a5, 16) SLOT_REDUCE(a6, 16) SLOT_REDUCE(a7, 16)
    SLOT_REDUCE(a0, 8)  SLOT_REDUCE(a1, 8)  SLOT_REDUCE(a2, 8)  SLOT_REDUCE(a3, 8)
    SLOT_REDUCE(a4, 8)  SLOT_REDUCE(a5, 8)  SLOT_REDUCE(a6, 8)  SLOT_REDUCE(a7, 8)

    if (lane < 8) {
        const float m0 = PRE ? dd : 1.0f;
        float r[16];
        r[0] = a0.x * m0;  r[1] = a0.y * m0;  r[2] = a1.x * m0;  r[3] = a1.y * m0;
        r[4] = a2.x * m0;  r[5] = a2.y * m0;  r[6] = a3.x * m0;  r[7] = a3.y * m0;
        r[8] = a4.x * m0;  r[9] = a4.y * m0;  r[10] = a5.x * m0; r[11] = a5.y * m0;
        r[12] = a6.x * m0; r[13] = a6.y * m0; r[14] = a7.x * m0; r[15] = a7.y * m0;

        // self-loop term from the f16 copy (full precision path)
        const uint4 uA = *(const uint4*)(Hf + (size_t)node * 128 + lane * 16);
        const uint4 uB = *(const uint4*)(Hf + (size_t)node * 128 + lane * 16 + 8);
        const float d2 = dd * dd;
        const unsigned hw[8] = {uA.x, uA.y, uA.z, uA.w, uB.x, uB.y, uB.z, uB.w};
#pragma unroll
        for (int i = 0; i < 8; ++i) {
            r[2 * i]     = fmaf(__low2float(u2h(hw[i])), d2, r[2 * i]);
            r[2 * i + 1] = fmaf(__high2float(u2h(hw[i])), d2, r[2 * i + 1]);
        }
        if (RELU_BIAS) {
            const float4 b0 = *(const float4*)(bias + lane * 16);
            const float4 b1 = *(const float4*)(bias + lane * 16 + 4);
            const float4 b2 = *(const float4*)(bias + lane * 16 + 8);
            const float4 b3 = *(const float4*)(bias + lane * 16 + 12);
            const float bb[16] = {b0.x, b0.y, b0.z, b0.w, b1.x, b1.y, b1.z, b1.w,
                                  b2.x, b2.y, b2.z, b2.w, b3.x, b3.y, b3.z, b3.w};
#pragma unroll
            for (int i = 0; i < 16; ++i) r[i] = fmaxf(r[i] + bb[i], 0.f);
        }
        uint4 o0, o1;
        o0.x = (unsigned)f2h(r[0]) | ((unsigned)f2h(r[1]) << 16);
        o0.y = (unsigned)f2h(r[2]) | ((unsigned)f2h(r[3]) << 16);
        o0.z = (unsigned)f2h(r[4]) | ((unsigned)f2h(r[5]) << 16);
        o0.w = (unsigned)f2h(r[6]) | ((unsigned)f2h(r[7]) << 16);
        o1.x = (unsigned)f2h(r[8]) | ((unsigned)f2h(r[9]) << 16);
        o1.y = (unsigned)f2h(r[10]) | ((unsigned)f2h(r[11]) << 16);
        o1.z = (unsigned)f2h(r[12]) | ((unsigned)f2h(r[13]) << 16);
        o1.w = (unsigned)f2h(r[14]) | ((unsigned)f2h(r[15]) << 16);
        *(uint4*)(Outf + (size_t)node * 128 + lane * 16) = o0;
        *(uint4*)(Outf + (size_t)node * 128 + lane * 16 + 8) = o1;
        if (W8) {
            // fp8 copy pre-scaled by dis[node] for the NEXT pull's add path
            int w0 = __builtin_amdgcn_cvt_pk_fp8_f32(r[0] * dd, r[1] * dd, 0, false);
            w0     = __builtin_amdgcn_cvt_pk_fp8_f32(r[2] * dd, r[3] * dd, w0, true);
            int w1 = __builtin_amdgcn_cvt_pk_fp8_f32(r[4] * dd, r[5] * dd, 0, false);
            w1     = __builtin_amdgcn_cvt_pk_fp8_f32(r[6] * dd, r[7] * dd, w1, true);
            int w2 = __builtin_amdgcn_cvt_pk_fp8_f32(r[8] * dd, r[9] * dd, 0, false);
            w2     = __builtin_amdgcn_cvt_pk_fp8_f32(r[10] * dd, r[11] * dd, w2, true);
            int w3 = __builtin_amdgcn_cvt_pk_fp8_f32(r[12] * dd, r[13] * dd, 0, false);
            w3     = __builtin_amdgcn_cvt_pk_fp8_f32(r[14] * dd, r[15] * dd, w3, true);
            *(uint4*)(Out8 + (size_t)node * 128 + lane * 16) =
                make_uint4((unsigned)w0, (unsigned)w1, (unsigned)w2, (unsigned)w3);
        }
    }
}

extern "C" void kernel_launch(void* const* d_in, const int* in_sizes, int n_in,
                              void* d_out, int out_size, void* d_ws, size_t ws_size,
                              hipStream_t stream) {
    const float* x   = (const float*)d_in[0];
    const int*   ei  = (const int*)d_in[1];
    const float* W1  = (const float*)d_in[2];
    const float* b1  = (const float*)d_in[3];
    const float* W2  = (const float*)d_in[4];
    const float* b2  = (const float*)d_in[5];
    const float* W3  = (const float*)d_in[6];
    const float* b3  = (const float*)d_in[7];
    float*       out = (float*)d_out;
    const int    N = N_NODES, E = N_EDGES;

    // workspace layout (bytes) — ~94 MB total
    char*           ws      = (char*)d_ws;
    int*            flag    = (int*)ws;                                    // 4 B
    int*            bcnt    = (int*)(ws + 4096);
    int*            bbase   = (int*)(ws + 16384);
    int*            bcur    = (int*)(ws + 32768);
    float*          dis     = (float*)(ws + 65536);                        // 400 KB
    int*            rowptr  = (int*)(ws + 524288);                         // 400 KB + 4
    unsigned short* Wt1     = (unsigned short*)(ws + 1 * (1u << 20));      // 32 KB
    unsigned short* Wt2     = Wt1 + 128 * 128;                             // 32 KB
    unsigned short* Wt3     = Wt2 + 128 * 128;                             // 12 KB
    unsigned*       eb      = (unsigned*)(ws + 2 * (size_t)(1u << 20));    // 6.4 MB (packed)
    int*            es      = (int*)(ws + 9 * (size_t)(1u << 20));         // 6.4 MB
    unsigned short* B1b     = (unsigned short*)(ws + 16 * (size_t)(1u << 20));  // 25.6 MB (f16)
    unsigned short* B2b     = (unsigned short*)(ws + 42 * (size_t)(1u << 20));  // 25.6 MB (f16)
    unsigned char*  B1e     = (unsigned char*)(ws + 68 * (size_t)(1u << 20));   // 12.8 MB (fp8)
    unsigned char*  B2e     = (unsigned char*)(ws + 81 * (size_t)(1u << 20));   // 12.8 MB (fp8)

    const int nscat = (E + CCHUNK - 1) / CCHUNK;   // 391
    const int gb    = (N + 63) / 64;               // 1563
    const int pg    = (N + 3) / 4;

    // ---- CSR build + weight prep ----
    k_detect<<<1, 256, 0, stream>>>(ei, flag);
    hipMemsetAsync(bcnt, 0, NBUCK * sizeof(int), stream);
    k_wt<<<(128 * 128 + 255) / 256, 256, 0, stream>>>(W1, Wt1, 128, 128);
    k_wt<<<(128 * 128 + 255) / 256, 256, 0, stream>>>(W2, Wt2, 128, 128);
    k_wt<<<(48 * 128 + 255) / 256, 256, 0, stream>>>(W3, Wt3, 40, 48);
    k_hist<<<512, 256, 0, stream>>>(ei, flag, bcnt, E);
    k_bscan<<<1, 1024, 0, stream>>>(bcnt, bbase, bcur, E);
    // scatter || layer-1 GEMM (independent work, one launch); fp8 out unscaled
    k_scat_gemm1<<<nscat + gb, 256, FUSED_LDS, stream>>>(ei, flag, bcur, eb, E, nscat, x, Wt1, B1b, B1e, N);
    k_build<<<NBUCK, 256, 0, stream>>>(bbase, eb, rowptr, es, dis, N, E);

    // ---- layer 1 aggregation (mul path: H1 fp8 unscaled) ----
    k_pull128<false, true, true><<<pg, 256, 0, stream>>>(rowptr, es, dis, B1e, B1b, b1, B2b, B2e, N);

    // ---- layer 2: GEMM (fp8 out pre-scaled), pull (add path) ----
    k_gemm_mfma<8, 1, 0><<<gb, 256, 0, stream>>>(B2b, Wt2, B1b, B1e, dis, nullptr, N, 128);
    k_pull128<true, true, true><<<pg, 256, 0, stream>>>(rowptr, es, dis, B1e, B1b, b2, B2b, B2e, N);

    // ---- layer 3: pull (add path, f16 out only) -> GEMM(W3)+bias+lsm ----
    k_pull128<true, false, false><<<pg, 256, 0, stream>>>(rowptr, es, dis, B2e, B2b, nullptr, B1b, nullptr, N);
    k_gemm_mfma<3, 1, 2><<<gb, 256, 0, stream>>>(B1b, Wt3, out, nullptr, nullptr, b3, N, 40);
}

// Round 12
// 274.620 us; speedup vs baseline: 1.1357x; 1.1357x over previous
//
#include <hip/hip_runtime.h>
#include <hip/hip_fp16.h>
#include <cstdint>

#define N_NODES 100000
#define N_EDGES 1600000
#define F_IN 128
#define HID 128
#define N_CLS 40
#define BSHIFT 7
#define NBUCK ((N_NODES + 127) >> 7)   // 782 buckets of 128 dst nodes
#define CCHUNK 4096                     // edges per scatter block
#define FUSED_LDS 52224                 // max(scatter 45280, gemm-NT8 52224)

typedef _Float16 f16x8 __attribute__((ext_vector_type(8)));
typedef __attribute__((ext_vector_type(4))) float f32x4;
typedef __attribute__((ext_vector_type(2))) float f32x2;

__device__ __forceinline__ unsigned short f2h(float f) {
    return __builtin_bit_cast(unsigned short, (_Float16)f);
}
__device__ __forceinline__ __half2 u2h(unsigned u) { return __builtin_bit_cast(__half2, u); }

// fp8 (OCP e4m3 on gfx950) pack/unpack via HW converts
__device__ __forceinline__ f32x2 fp8_lo(unsigned u) { return __builtin_amdgcn_cvt_pk_f32_fp8((int)u, false); }
__device__ __forceinline__ f32x2 fp8_hi(unsigned u) { return __builtin_amdgcn_cvt_pk_f32_fp8((int)u, true); }
__device__ __forceinline__ unsigned char f2e(float v) {
    return (unsigned char)(__builtin_amdgcn_cvt_pk_fp8_f32(v, v, 0, false) & 0xff);
}

// ---------------------------------------------------------------------------
// Edge dtype detection (int64 vs int32 edge_index). Deterministic.
// ---------------------------------------------------------------------------
__global__ __launch_bounds__(256) void k_detect(const int* __restrict__ e, int* __restrict__ flag) {
    __shared__ int sor;
    if (threadIdx.x == 0) sor = 0;
    __syncthreads();
    atomicOr(&sor, e[threadIdx.x * 2 + 1]);
    __syncthreads();
    if (threadIdx.x == 0) flag[0] = (sor == 0) ? 1 : 0;  // 1 = int64 layout
}

__device__ __forceinline__ int edge_at(const int* e, const int* flag, int which, int i) {
    return flag[0] ? e[2 * ((size_t)which * N_EDGES + i)] : e[(size_t)which * N_EDGES + i];
}

// ---------------------------------------------------------------------------
// Bucketed CSR build. Phase A: per-bucket histogram.
// ---------------------------------------------------------------------------
__global__ __launch_bounds__(256) void k_hist(const int* __restrict__ e, const int* __restrict__ flag,
                                              int* __restrict__ bcnt, int E) {
    __shared__ int h[NBUCK];
    for (int i = threadIdx.x; i < NBUCK; i += 256) h[i] = 0;
    __syncthreads();
    for (int i = blockIdx.x * 256 + threadIdx.x; i < E; i += gridDim.x * 256) {
        int d = edge_at(e, flag, 1, i);
        atomicAdd(&h[d >> BSHIFT], 1);
    }
    __syncthreads();
    for (int i = threadIdx.x; i < NBUCK; i += 256)
        if (h[i]) atomicAdd(&bcnt[i], h[i]);
}

// Phase B: single-block scan of bucket counts -> bucket bases + cursors.
__global__ __launch_bounds__(1024) void k_bscan(const int* __restrict__ bcnt, int* __restrict__ bbase,
                                                int* __restrict__ bcur, int E) {
    __shared__ int s0[1024], s1[1024];
    int t = threadIdx.x;
    s0[t] = (t < NBUCK) ? bcnt[t] : 0;
    __syncthreads();
    int* src = s0;
    int* dst = s1;
    for (int off = 1; off < 1024; off <<= 1) {
        dst[t] = src[t] + ((t >= off) ? src[t - off] : 0);
        __syncthreads();
        int* tmp = src; src = dst; dst = tmp;
    }
    if (t < NBUCK) {
        int ex = t ? src[t - 1] : 0;
        bbase[t] = ex;
        bcur[t]  = ex;
    }
    if (t == 0) bbase[NBUCK] = E;
}

// Phase C body: LDS-binned scatter; global eb packed as (s<<7)|(d&127).
__device__ __forceinline__ void scatter_body(char* smem, const int* __restrict__ e,
                                             const int* __restrict__ flag, int* __restrict__ bcur,
                                             unsigned* __restrict__ eb, int E, int blk) {
    uint2* st  = (uint2*)smem;              // 32768 B
    int* hA    = (int*)(smem + 32768);      // NBUCK ints each
    int* hB    = hA + NBUCK;
    int* cur   = hB + NBUCK;
    int* runb  = cur + NBUCK;
    const int t    = threadIdx.x;
    const int base = blk * CCHUNK;
    const int len  = min(CCHUNK, E - base);

    for (int i = t; i < NBUCK; i += 256) hA[i] = 0;
    __syncthreads();
    for (int i = t; i < len; i += 256) {
        int d = edge_at(e, flag, 1, base + i);
        atomicAdd(&hA[d >> BSHIFT], 1);
    }
    __syncthreads();
    int* src = hA;
    int* dst = hB;
    for (int off = 1; off < NBUCK; off <<= 1) {
        for (int i = t; i < NBUCK; i += 256)
            dst[i] = src[i] + ((i >= off) ? src[i - off] : 0);
        __syncthreads();
        int* tmp = src; src = dst; dst = tmp;
    }
    for (int i = t; i < NBUCK; i += 256) {
        int inc = src[i];
        int ex  = i ? src[i - 1] : 0;
        dst[i] = ex;
        cur[i] = ex;
        int c = inc - ex;
        if (c) runb[i] = atomicAdd(&bcur[i], c);
    }
    __syncthreads();
    for (int i = t; i < len; i += 256) {
        int s = edge_at(e, flag, 0, base + i);
        int d = edge_at(e, flag, 1, base + i);
        int pos = atomicAdd(&cur[d >> BSHIFT], 1);
        st[pos] = make_uint2((unsigned)s, (unsigned)d);
    }
    __syncthreads();
    for (int i = t; i < len; i += 256) {
        uint2 v = st[i];
        int   b = (int)(v.y >> BSHIFT);
        int   gpos = runb[b] + (i - dst[b]);
        eb[gpos] = (v.x << 7) | (v.y & 127u);
    }
}

// Phase D: one block per bucket; exact per-dst CSR; fuses degree->dis/rowptr.
__global__ __launch_bounds__(256) void k_build(const int* __restrict__ bbase, const unsigned* __restrict__ eb,
                                               int* __restrict__ rowptr, int* __restrict__ es,
                                               float* __restrict__ dis, int N, int E) {
    __shared__ int c0[128], c1[128], cur[128];
    const int b  = blockIdx.x;
    const int t  = threadIdx.x;
    const int lo = bbase[b], hi = bbase[b + 1];

    if (t < 128) c0[t] = 0;
    __syncthreads();
    for (int i = lo + t; i < hi; i += 256) atomicAdd(&c0[eb[i] & 127u], 1);
    __syncthreads();
    int* src = c0;
    int* dst = c1;
    for (int off = 1; off < 128; off <<= 1) {
        if (t < 128) dst[t] = src[t] + ((t >= off) ? src[t - off] : 0);
        __syncthreads();
        int* tmp = src; src = dst; dst = tmp;
    }
    if (t < 128) {
        int inc = src[t], ex = t ? src[t - 1] : 0;
        int node = (b << BSHIFT) + t;
        if (node < N) {
            rowptr[node] = lo + ex;
            dis[node]    = rsqrtf((float)(inc - ex + 1));
        }
        cur[t] = ex;
    }
    if (b == 0 && t == 0) rowptr[N] = E;
    __syncthreads();
    for (int i = lo + t; i < hi; i += 256) {
        unsigned v = eb[i];
        int pos = atomicAdd(&cur[v & 127u], 1);
        es[lo + pos] = (int)(v >> 7);
    }
}

// Wt[col][k] = f16(W[k][col]), zero-padded to outp cols
__global__ __launch_bounds__(256) void k_wt(const float* __restrict__ W, unsigned short* __restrict__ Wt,
                                            int outc, int outp) {
    int idx = blockIdx.x * 256 + threadIdx.x;
    if (idx >= outp * 128) return;
    int col = idx >> 7, k = idx & 127;
    Wt[idx] = (col < outc) ? f2h(W[(size_t)k * outc + col]) : (unsigned short)0;
}

// ---------------------------------------------------------------------------
// MFMA f16 GEMM core. INMODE: 0 = fp32 in, 1 = f16 in. OUTMODE: 0 = f16 out
// [N,128] + fp8 copy (prescaled by dis[row] when dis8 != null); 2 = fused
// bias + log_softmax, fp32 out [N,outc]. Block = 64 rows, 4 waves x 16 rows.
// ---------------------------------------------------------------------------
template <int NT, int INMODE, int OUTMODE>
__device__ __forceinline__ void gemm_core(char* smemraw, const void* __restrict__ Xv,
                                          const unsigned short* __restrict__ Wt,
                                          void* __restrict__ HoutV, unsigned char* __restrict__ O8,
                                          const float* __restrict__ dis8,
                                          const float* __restrict__ bias, int N, int outc, int blk) {
    constexpr int OUTP = NT * 16;
    unsigned short* sX = (unsigned short*)smemraw;   // 64*136
    unsigned short* sW = sX + 64 * 136;              // OUTP*136
    const int tid  = threadIdx.x;
    const int row0 = blk * 64;

    if (INMODE == 0) {
        const float* X = (const float*)Xv;
        for (int c = tid; c < 64 * 16; c += 256) {
            int r = c >> 4, off = c & 15, row = row0 + r;
            unsigned short tmp[8];
            if (row < N) {
                const float* p = X + (size_t)row * 128 + off * 8;
                const float4 pa = *(const float4*)p;
                const float4 pb = *(const float4*)(p + 4);
                tmp[0] = f2h(pa.x); tmp[1] = f2h(pa.y); tmp[2] = f2h(pa.z); tmp[3] = f2h(pa.w);
                tmp[4] = f2h(pb.x); tmp[5] = f2h(pb.y); tmp[6] = f2h(pb.z); tmp[7] = f2h(pb.w);
            } else {
#pragma unroll
                for (int j = 0; j < 8; ++j) tmp[j] = 0;
            }
            *(uint4*)(&sX[r * 136 + off * 8]) = *(uint4*)tmp;
        }
    } else {
        const unsigned short* X = (const unsigned short*)Xv;
        for (int c = tid; c < 64 * 16; c += 256) {
            int r = c >> 4, off = c & 15, row = row0 + r;
            uint4 v = make_uint4(0, 0, 0, 0);
            if (row < N) v = *(const uint4*)(X + (size_t)row * 128 + off * 8);
            *(uint4*)(&sX[r * 136 + off * 8]) = v;
        }
    }
    for (int c = tid; c < OUTP * 16; c += 256) {
        int r = c >> 4, off = c & 15;
        *(uint4*)(&sW[r * 136 + off * 8]) = *(const uint4*)(Wt + (size_t)r * 128 + off * 8);
    }
    __syncthreads();

    const int wave = tid >> 6, lane = tid & 63;
    const int l15 = lane & 15, g = lane >> 4;
    const int arow = (wave << 4) + l15;

    f32x4 acc[NT];
#pragma unroll
    for (int n = 0; n < NT; ++n) acc[n] = (f32x4){0.f, 0.f, 0.f, 0.f};

#pragma unroll
    for (int kk = 0; kk < 4; ++kk) {
        f16x8 a = *(const f16x8*)(&sX[arow * 136 + kk * 32 + g * 8]);
#pragma unroll
        for (int n = 0; n < NT; ++n) {
            f16x8 b = *(const f16x8*)(&sW[(n * 16 + l15) * 136 + kk * 32 + g * 8]);
            acc[n] = __builtin_amdgcn_mfma_f32_16x16x32_f16(a, b, acc[n], 0, 0, 0);
        }
    }

    if (OUTMODE == 0) {
        unsigned short* O = (unsigned short*)HoutV;
        float sc4[4];
#pragma unroll
        for (int r = 0; r < 4; ++r) {
            int row = row0 + (wave << 4) + g * 4 + r;
            sc4[r] = (dis8 && row < N) ? dis8[row] : 1.0f;
        }
#pragma unroll
        for (int n = 0; n < NT; ++n) {
#pragma unroll
            for (int r = 0; r < 4; ++r) {
                int row = row0 + (wave << 4) + g * 4 + r;
                if (row < N) {
                    O[(size_t)row * 128 + n * 16 + l15]  = f2h(acc[n][r]);
                    O8[(size_t)row * 128 + n * 16 + l15] = f2e(acc[n][r] * sc4[r]);
                }
            }
        }
    } else {
        // fused bias + log_softmax epilogue
        float* O = (float*)HoutV;
#pragma unroll
        for (int r = 0; r < 4; ++r) {
            int row = row0 + (wave << 4) + g * 4 + r;
            float v[NT];
            float m = -3.0e38f;
#pragma unroll
            for (int n = 0; n < NT; ++n) {
                int col = n * 16 + l15;
                v[n] = (col < outc) ? acc[n][r] + bias[col] : -3.0e38f;
                m = fmaxf(m, v[n]);
            }
            for (int off = 8; off; off >>= 1) m = fmaxf(m, __shfl_xor(m, off));
            float ssum = 0.f;
#pragma unroll
            for (int n = 0; n < NT; ++n) {
                int col = n * 16 + l15;
                ssum += (col < outc) ? __expf(v[n] - m) : 0.f;
            }
            for (int off = 8; off; off >>= 1) ssum += __shfl_xor(ssum, off);
            float ls = __logf(ssum);
            if (row < N) {
#pragma unroll
                for (int n = 0; n < NT; ++n) {
                    int col = n * 16 + l15;
                    if (col < outc) O[(size_t)row * outc + col] = v[n] - m - ls;
                }
            }
        }
    }
}

template <int NT, int INMODE, int OUTMODE>
__global__ __launch_bounds__(256) void k_gemm_mfma(const void* __restrict__ Xv,
                                                   const unsigned short* __restrict__ Wt,
                                                   void* __restrict__ HoutV, unsigned char* __restrict__ O8,
                                                   const float* __restrict__ dis8,
                                                   const float* __restrict__ bias, int N, int outc) {
    constexpr int SZ = 64 * 136 * 2 + NT * 16 * 136 * 2;
    __shared__ __align__(16) char smem[SZ];
    gemm_core<NT, INMODE, OUTMODE>(smem, Xv, Wt, HoutV, O8, dis8, bias, N, outc, blockIdx.x);
}

// Fused: CSR scatter (blocks [0,nscat)) || layer-1 GEMM (blocks [nscat, ...)).
__global__ __launch_bounds__(256) void k_scat_gemm1(const int* __restrict__ e, const int* __restrict__ flag,
                                                    int* __restrict__ bcur, unsigned* __restrict__ eb, int E,
                                                    int nscat, const float* __restrict__ x,
                                                    const unsigned short* __restrict__ Wt1,
                                                    unsigned short* __restrict__ B1b,
                                                    unsigned char* __restrict__ B1e, int N) {
    extern __shared__ __align__(16) char smem[];
    if ((int)blockIdx.x < nscat)
        scatter_body(smem, e, flag, bcur, eb, E, blockIdx.x);
    else
        gemm_core<8, 0, 0>(smem, x, Wt1, B1b, B1e, nullptr, nullptr, N, 128, blockIdx.x - nscat);
}

// ---------------------------------------------------------------------------
// CSR pull, 4-slot uint2 gather (r9/r10 structure — measured best): lane =
// (edge-slot q = lane>>4, feat-octet f = lane&15); one uint2 (8 fp8 feats)
// per lane -> wave covers 4 edges per load. PRE = rows pre-scaled by
// dis[src] (pure-add inner loop). Cross-slot reduce: shfl_xor 32/16.
// ---------------------------------------------------------------------------
#define PSTEP(JJ)                                                            \
    {                                                                        \
        int s = __shfl(sv, (JJ) + q);                                        \
        const uint2 u = *(const uint2*)(H8 + (size_t)s * 128 + f * 8);       \
        if (PRE) {                                                           \
            a0 += fp8_lo(u.x); a1 += fp8_hi(u.x);                            \
            a2 += fp8_lo(u.y); a3 += fp8_hi(u.y);                            \
        } else {                                                             \
            float n = __shfl(nv, (JJ) + q);                                  \
            f32x2 nn = {n, n};                                               \
            a0 += fp8_lo(u.x) * nn; a1 += fp8_hi(u.x) * nn;                  \
            a2 += fp8_lo(u.y) * nn; a3 += fp8_hi(u.y) * nn;                  \
        }                                                                    \
    }

#define PSTEPC(JJ)                                                           \
    {                                                                        \
        int  idx = (JJ) + q;                                                 \
        bool ok  = idx < len;                                                \
        int  s   = __shfl(sv, ok ? idx : len - 1);                           \
        uint2 u  = *(const uint2*)(H8 + (size_t)s * 128 + f * 8);            \
        if (!ok) { u.x = 0u; u.y = 0u; }                                     \
        if (PRE) {                                                           \
            a0 += fp8_lo(u.x); a1 += fp8_hi(u.x);                            \
            a2 += fp8_lo(u.y); a3 += fp8_hi(u.y);                            \
        } else {                                                             \
            float n = __shfl(nv, ok ? idx : len - 1);                        \
            f32x2 nn = {n, n};                                               \
            a0 += fp8_lo(u.x) * nn; a1 += fp8_hi(u.x) * nn;                  \
            a2 += fp8_lo(u.y) * nn; a3 += fp8_hi(u.y) * nn;                  \
        }                                                                    \
    }

#define SLOT_REDUCE(A, M) { A.x += __shfl_xor(A.x, M); A.y += __shfl_xor(A.y, M); }

// Standalone pull. PRE = add path; RELU_BIAS for layers 1/2; W8 writes fp8
// copy pre-scaled by dis[node] for the next pull's add path.
template <bool PRE, bool RELU_BIAS, bool W8>
__global__ __launch_bounds__(256) void k_pull128(const int* __restrict__ rowptr, const int* __restrict__ es,
                                                 const float* __restrict__ dis,
                                                 const unsigned char* __restrict__ H8,
                                                 const unsigned short* __restrict__ Hf,
                                                 const float* __restrict__ bias,
                                                 unsigned short* __restrict__ Outf,
                                                 unsigned char* __restrict__ Out8, int N) {
    int node = blockIdx.x * 4 + (threadIdx.x >> 6);
    if (node >= N) return;
    const int lane = threadIdx.x & 63;
    const int q = lane >> 4, f = lane & 15;
    const float dd = dis[node];

    f32x2 a0 = {0.f, 0.f}, a1 = a0, a2 = a0, a3 = a0;

    const int beg = rowptr[node], end = rowptr[node + 1];
    for (int c = beg; c < end; c += 64) {
        int len = end - c;
        if (len > 64) len = 64;
        int   sv = es[c + (lane < len ? lane : len - 1)];
        float nv = 0.f;
        if (!PRE) nv = dis[sv] * dd;
        int j = 0;
        for (; j + 16 <= len; j += 16) { PSTEP(j) PSTEP(j + 4) PSTEP(j + 8) PSTEP(j + 12) }
        for (; j + 8 <= len; j += 8) { PSTEP(j) PSTEP(j + 4) }
        for (; j < len; j += 4) PSTEPC(j)
    }

    SLOT_REDUCE(a0, 32) SLOT_REDUCE(a1, 32) SLOT_REDUCE(a2, 32) SLOT_REDUCE(a3, 32)
    SLOT_REDUCE(a0, 16) SLOT_REDUCE(a1, 16) SLOT_REDUCE(a2, 16) SLOT_REDUCE(a3, 16)

    if (lane < 16) {
        const float m0 = PRE ? dd : 1.0f;
        float r0 = a0.x * m0, r1 = a0.y * m0, r2 = a1.x * m0, r3 = a1.y * m0;
        float r4 = a2.x * m0, r5 = a2.y * m0, r6 = a3.x * m0, r7 = a3.y * m0;
        // self-loop term from the f16 copy (full precision path)
        const uint4 u  = *(const uint4*)(Hf + (size_t)node * 128 + lane * 8);
        const float d2 = dd * dd;
        r0 = fmaf(__low2float(u2h(u.x)), d2, r0);  r1 = fmaf(__high2float(u2h(u.x)), d2, r1);
        r2 = fmaf(__low2float(u2h(u.y)), d2, r2);  r3 = fmaf(__high2float(u2h(u.y)), d2, r3);
        r4 = fmaf(__low2float(u2h(u.z)), d2, r4);  r5 = fmaf(__high2float(u2h(u.z)), d2, r5);
        r6 = fmaf(__low2float(u2h(u.w)), d2, r6);  r7 = fmaf(__high2float(u2h(u.w)), d2, r7);
        if (RELU_BIAS) {
            const float4 bA = *(const float4*)(bias + lane * 8);
            const float4 bB = *(const float4*)(bias + lane * 8 + 4);
            r0 = fmaxf(r0 + bA.x, 0.f); r1 = fmaxf(r1 + bA.y, 0.f);
            r2 = fmaxf(r2 + bA.z, 0.f); r3 = fmaxf(r3 + bA.w, 0.f);
            r4 = fmaxf(r4 + bB.x, 0.f); r5 = fmaxf(r5 + bB.y, 0.f);
            r6 = fmaxf(r6 + bB.z, 0.f); r7 = fmaxf(r7 + bB.w, 0.f);
        }
        uint4 o;
        o.x = (unsigned)f2h(r0) | ((unsigned)f2h(r1) << 16);
        o.y = (unsigned)f2h(r2) | ((unsigned)f2h(r3) << 16);
        o.z = (unsigned)f2h(r4) | ((unsigned)f2h(r5) << 16);
        o.w = (unsigned)f2h(r6) | ((unsigned)f2h(r7) << 16);
        *(uint4*)(Outf + (size_t)node * 128 + lane * 8) = o;
        if (W8) {
            // fp8 copy pre-scaled by dis[node] for the NEXT pull's add path
            int w0 = __builtin_amdgcn_cvt_pk_fp8_f32(r0 * dd, r1 * dd, 0, false);
            w0     = __builtin_amdgcn_cvt_pk_fp8_f32(r2 * dd, r3 * dd, w0, true);
            int w1 = __builtin_amdgcn_cvt_pk_fp8_f32(r4 * dd, r5 * dd, 0, false);
            w1     = __builtin_amdgcn_cvt_pk_fp8_f32(r6 * dd, r7 * dd, w1, true);
            *(uint2*)(Out8 + (size_t)node * 128 + lane * 8) = make_uint2((unsigned)w0, (unsigned)w1);
        }
    }
}

extern "C" void kernel_launch(void* const* d_in, const int* in_sizes, int n_in,
                              void* d_out, int out_size, void* d_ws, size_t ws_size,
                              hipStream_t stream) {
    const float* x   = (const float*)d_in[0];
    const int*   ei  = (const int*)d_in[1];
    const float* W1  = (const float*)d_in[2];
    const float* b1  = (const float*)d_in[3];
    const float* W2  = (const float*)d_in[4];
    const float* b2  = (const float*)d_in[5];
    const float* W3  = (const float*)d_in[6];
    const float* b3  = (const float*)d_in[7];
    float*       out = (float*)d_out;
    const int    N = N_NODES, E = N_EDGES;

    // workspace layout (bytes) — ~94 MB total
    char*           ws      = (char*)d_ws;
    int*            flag    = (int*)ws;                                    // 4 B
    int*            bcnt    = (int*)(ws + 4096);
    int*            bbase   = (int*)(ws + 16384);
    int*            bcur    = (int*)(ws + 32768);
    float*          dis     = (float*)(ws + 65536);                        // 400 KB
    int*            rowptr  = (int*)(ws + 524288);                         // 400 KB + 4
    unsigned short* Wt1     = (unsigned short*)(ws + 1 * (1u << 20));      // 32 KB
    unsigned short* Wt2     = Wt1 + 128 * 128;                             // 32 KB
    unsigned short* Wt3     = Wt2 + 128 * 128;                             // 12 KB
    unsigned*       eb      = (unsigned*)(ws + 2 * (size_t)(1u << 20));    // 6.4 MB (packed)
    int*            es      = (int*)(ws + 9 * (size_t)(1u << 20));         // 6.4 MB
    unsigned short* B1b     = (unsigned short*)(ws + 16 * (size_t)(1u << 20));  // 25.6 MB (f16)
    unsigned short* B2b     = (unsigned short*)(ws + 42 * (size_t)(1u << 20));  // 25.6 MB (f16)
    unsigned char*  B1e     = (unsigned char*)(ws + 68 * (size_t)(1u << 20));   // 12.8 MB (fp8)
    unsigned char*  B2e     = (unsigned char*)(ws + 81 * (size_t)(1u << 20));   // 12.8 MB (fp8)

    const int nscat = (E + CCHUNK - 1) / CCHUNK;   // 391
    const int gb    = (N + 63) / 64;               // 1563
    const int pg    = (N + 3) / 4;

    // ---- CSR build + weight prep ----
    k_detect<<<1, 256, 0, stream>>>(ei, flag);
    hipMemsetAsync(bcnt, 0, NBUCK * sizeof(int), stream);
    k_wt<<<(128 * 128 + 255) / 256, 256, 0, stream>>>(W1, Wt1, 128, 128);
    k_wt<<<(128 * 128 + 255) / 256, 256, 0, stream>>>(W2, Wt2, 128, 128);
    k_wt<<<(48 * 128 + 255) / 256, 256, 0, stream>>>(W3, Wt3, 40, 48);
    k_hist<<<512, 256, 0, stream>>>(ei, flag, bcnt, E);
    k_bscan<<<1, 1024, 0, stream>>>(bcnt, bbase, bcur, E);
    // scatter || layer-1 GEMM (independent work, one launch); fp8 out unscaled
    k_scat_gemm1<<<nscat + gb, 256, FUSED_LDS, stream>>>(ei, flag, bcur, eb, E, nscat, x, Wt1, B1b, B1e, N);
    k_build<<<NBUCK, 256, 0, stream>>>(bbase, eb, rowptr, es, dis, N, E);

    // ---- layer 1 aggregation (mul path: H1 fp8 unscaled) ----
    k_pull128<false, true, true><<<pg, 256, 0, stream>>>(rowptr, es, dis, B1e, B1b, b1, B2b, B2e, N);

    // ---- layer 2: GEMM (fp8 out pre-scaled), pull (add path) ----
    k_gemm_mfma<8, 1, 0><<<gb, 256, 0, stream>>>(B2b, Wt2, B1b, B1e, dis, nullptr, N, 128);
    k_pull128<true, true, true><<<pg, 256, 0, stream>>>(rowptr, es, dis, B1e, B1b, b2, B2b, B2e, N);

    // ---- layer 3: pull (add path, f16 out only) -> GEMM(W3)+bias+lsm ----
    k_pull128<true, false, false><<<pg, 256, 0, stream>>>(rowptr, es, dis, B2e, B2b, nullptr, B1b, nullptr, N);
    k_gemm_mfma<3, 1, 2><<<gb, 256, 0, stream>>>(B1b, Wt3, out, nullptr, nullptr, b3, N, 40);
}